// Round 1
// baseline (6473.483 us; speedup 1.0000x reference)
//
#include <hip/hip_runtime.h>
#include <cstdint>

// ---------------------------------------------------------------------------
// Constants for this problem
//   HEADS=16, DIM=1024, SEQ_LEN=512, MEM_LEN=512, CMEM_LEN=128, CMEM_RATIO=4
//   DIM_H=64, b=8, kv_len=1152
// ---------------------------------------------------------------------------

#define GKT 16

// Generic tiled fp32 GEMM: C[M,N] = A[M,K] @ B[K,N] (+bias per col)
// Batched via blockIdx.z with z -> (zb = z/H, zh = z%H) offsets.
// amode==1: A rows gathered from concat(cmem[128], mem[512], x[512]) per batch of 1152 rows.
__global__ __launch_bounds__(256)
void gemm_kernel(const float* __restrict__ A, const float* __restrict__ B, float* __restrict__ C,
                 int M, int N, int K,
                 int lda, int ldb, int ldc,
                 long a_s0, long a_s1, long b_s0, long b_s1, long c_s0, long c_s1,
                 int H, const float* __restrict__ bias, int amode,
                 const float* __restrict__ g_cmem, const float* __restrict__ g_mem,
                 const float* __restrict__ g_x)
{
    int z = blockIdx.z;
    int zb = z / H, zh = z % H;
    const float* Ab = A + zb * a_s0 + zh * a_s1;
    const float* Bb = B + zb * b_s0 + zh * b_s1;
    float* Cb = C + zb * c_s0 + zh * c_s1;

    int row0 = blockIdx.y * 64, col0 = blockIdx.x * 64;
    int tid = threadIdx.x;
    int ty = tid >> 4, tx = tid & 15;

    __shared__ float As[GKT][65];
    __shared__ float Bs[GKT][65];

    float acc[4][4];
#pragma unroll
    for (int i = 0; i < 4; i++)
#pragma unroll
        for (int j = 0; j < 4; j++) acc[i][j] = 0.f;

    for (int k0 = 0; k0 < K; k0 += GKT) {
#pragma unroll
        for (int t = 0; t < 4; t++) {
            int e = tid + 256 * t;
            int m = e >> 4, kk = e & 15;
            int gr = row0 + m;
            float v = 0.f;
            if (gr < M) {
                if (amode == 0) {
                    v = Ab[(long)gr * lda + k0 + kk];
                } else {
                    int bb = gr / 1152, r = gr % 1152;
                    const float* src = (r < 128) ? (g_cmem + ((long)bb * 128 + r) * 1024)
                                     : (r < 640) ? (g_mem + ((long)bb * 512 + (r - 128)) * 1024)
                                                 : (g_x   + ((long)bb * 512 + (r - 640)) * 1024);
                    v = src[k0 + kk];
                }
            }
            As[kk][m] = v;
        }
#pragma unroll
        for (int t = 0; t < 4; t++) {
            int e = tid + 256 * t;
            int kk = e >> 6, n = e & 63;
            int gc = col0 + n;
            float v = 0.f;
            if (gc < N) v = Bb[(long)(k0 + kk) * ldb + gc];
            Bs[kk][n] = v;
        }
        __syncthreads();
#pragma unroll
        for (int kk = 0; kk < GKT; kk++) {
            float a_[4], b_[4];
#pragma unroll
            for (int i = 0; i < 4; i++) a_[i] = As[kk][ty + 16 * i];
#pragma unroll
            for (int j = 0; j < 4; j++) b_[j] = Bs[kk][tx + 16 * j];
#pragma unroll
            for (int i = 0; i < 4; i++)
#pragma unroll
                for (int j = 0; j < 4; j++) acc[i][j] += a_[i] * b_[j];
        }
        __syncthreads();
    }

#pragma unroll
    for (int i = 0; i < 4; i++) {
        int gr = row0 + ty + 16 * i;
        if (gr >= M) continue;
#pragma unroll
        for (int j = 0; j < 4; j++) {
            int gc = col0 + tx + 16 * j;
            if (gc >= N) continue;
            float v = acc[i][j];
            if (bias) v += bias[gc];
            Cb[(long)gr * ldc + gc] = v;
        }
    }
}

// conv_w (o=1024, i=1024, r=4) -> convwT[(r*1024+i), o]
__global__ __launch_bounds__(256)
void transpose_convw(const float* __restrict__ cw, float* __restrict__ wt)
{
    int idx = blockIdx.x;            // idx = r*1024 + i
    int r = idx >> 10, i = idx & 1023;
    for (int o = threadIdx.x; o < 1024; o += 256)
        wt[(long)idx * 1024 + o] = cw[((long)o * 1024 + i) * 4 + r];
}

// dots[b,h,r,c] = 0.125*( q_h[r]·k_h[c] + q_h[r]·pe_h[c+511-r] [if <1152 else 0] )
__global__ __launch_bounds__(256)
void dots_kernel(const float* __restrict__ q, const float* __restrict__ kv,
                 const float* __restrict__ pe, float* __restrict__ W)
{
    int z = blockIdx.z;             // b*16 + h
    int b = z >> 4, h = z & 15;
    int r0 = blockIdx.y * 32, c0 = blockIdx.x * 32;
    int tid = threadIdx.x;

    __shared__ float qs[32][65];
    __shared__ float ks[32][65];
    __shared__ float pes[64][65];

#pragma unroll
    for (int t = 0; t < 8; t++) {
        int e = tid + 256 * t; int rr = e >> 6, d = e & 63;
        qs[rr][d] = q[((long)(b * 512 + r0 + rr)) * 1024 + h * 64 + d];
    }
#pragma unroll
    for (int t = 0; t < 8; t++) {
        int e = tid + 256 * t; int cc = e >> 6, d = e & 63;
        ks[cc][d] = kv[((long)(b * 1152 + c0 + cc)) * 2048 + h * 64 + d];
    }
    int jjb = c0 - r0 + 480;
#pragma unroll
    for (int t = 0; t < 16; t++) {
        int e = tid + 256 * t; int u = e >> 6, d = e & 63;
        int jj = jjb + u;
        pes[u][d] = (jj >= 0 && jj < 1152) ? pe[((long)(h * 1152 + jj)) * 64 + d] : 0.f;
    }
    __syncthreads();

    int cc = tid & 31, ty = tid >> 5;     // ty in 0..7
#pragma unroll
    for (int s = 0; s < 4; s++) {
        int rr = ty + 8 * s;
        int u = cc - rr + 31;             // 0..62
        float dot = 0.f;
#pragma unroll
        for (int d = 0; d < 64; d++) {
            float qv = qs[rr][d];
            dot += qv * ks[cc][d];
            dot += qv * pes[u][d];
        }
        W[((long)z * 512 + r0 + rr) * 1152 + c0 + cc] = 0.125f * dot;
    }
}

// row softmax over 1152, in place
__global__ __launch_bounds__(256)
void softmax_kernel(float* __restrict__ W)
{
    long row = blockIdx.x;
    float* p = W + row * 1152;
    __shared__ float buf[1152];
    __shared__ float red[5];
    int tid = threadIdx.x;

    float mx = -3.4e38f;
    for (int c = tid; c < 1152; c += 256) { float v = p[c]; buf[c] = v; mx = fmaxf(mx, v); }
#pragma unroll
    for (int off = 32; off; off >>= 1) mx = fmaxf(mx, __shfl_xor(mx, off, 64));
    if ((tid & 63) == 0) red[tid >> 6] = mx;
    __syncthreads();
    if (tid == 0) red[4] = fmaxf(fmaxf(red[0], red[1]), fmaxf(red[2], red[3]));
    __syncthreads();
    float M = red[4];
    __syncthreads();

    float sm = 0.f;
    for (int c = tid; c < 1152; c += 256) { float e = expf(buf[c] - M); buf[c] = e; sm += e; }
#pragma unroll
    for (int off = 32; off; off >>= 1) sm += __shfl_xor(sm, off, 64);
    if ((tid & 63) == 0) red[tid >> 6] = sm;
    __syncthreads();
    if (tid == 0) red[4] = red[0] + red[1] + red[2] + red[3];
    __syncthreads();
    float inv = 1.f / red[4];
    for (int c = tid; c < 1152; c += 256) p[c] = buf[c] * inv;
}

// fused aux: || full_attn(q, k[128:640], v[128:640]) - full_attn(q, ck, cv) ||^2 per block tile
__global__ __launch_bounds__(256)
void aux_attn_kernel(const float* __restrict__ q, const float* __restrict__ kv,
                     const float* __restrict__ ckv, float* __restrict__ partials)
{
    int z = blockIdx.y;                 // b*16 + h
    int b = z >> 4, h = z & 15;
    int r0 = blockIdx.x * 16;
    int tid = threadIdx.x;

    __shared__ float qs[16][65];
    __shared__ float ks[64][65];
    __shared__ float sc[16][512];
    __shared__ float rowsum[16];
    __shared__ float wred[4];

#pragma unroll
    for (int t = 0; t < 4; t++) {
        int e = tid + 256 * t; int rr = e >> 6, d = e & 63;
        qs[rr][d] = q[((long)(b * 512 + r0 + rr)) * 1024 + h * 64 + d];
    }

    float o1[4], o2[4];
    int jj = tid & 63, w = tid >> 6;

    // ---------- attention 1: old_mem k/v = kv rows 128..639 ----------
    for (int jt = 0; jt < 8; jt++) {
        __syncthreads();
#pragma unroll
        for (int t = 0; t < 16; t++) {
            int e = tid + 256 * t; int j = e >> 6, d = e & 63;
            ks[j][d] = kv[((long)(b * 1152 + 128 + jt * 64 + j)) * 2048 + h * 64 + d];
        }
        __syncthreads();
#pragma unroll
        for (int s = 0; s < 4; s++) {
            int rr = w * 4 + s;
            float dot = 0.f;
#pragma unroll
            for (int d = 0; d < 64; d++) dot += qs[rr][d] * ks[jj][d];
            sc[rr][jt * 64 + jj] = dot * 0.125f;
        }
    }
    __syncthreads();
    {   // softmax rows over 512 (16 threads per row)
        int row = tid >> 4, l = tid & 15;
        float mx = -3.4e38f;
        for (int c = l; c < 512; c += 16) mx = fmaxf(mx, sc[row][c]);
#pragma unroll
        for (int off = 8; off; off >>= 1) mx = fmaxf(mx, __shfl_xor(mx, off, 16));
        float sm = 0.f;
        for (int c = l; c < 512; c += 16) { float e = expf(sc[row][c] - mx); sc[row][c] = e; sm += e; }
#pragma unroll
        for (int off = 8; off; off >>= 1) sm += __shfl_xor(sm, off, 16);
        if (l == 0) rowsum[row] = sm;
    }
#pragma unroll
    for (int s = 0; s < 4; s++) o1[s] = 0.f;
    for (int jt = 0; jt < 8; jt++) {
        __syncthreads();
#pragma unroll
        for (int t = 0; t < 16; t++) {
            int e = tid + 256 * t; int j = e >> 6, d = e & 63;
            ks[j][d] = kv[((long)(b * 1152 + 128 + jt * 64 + j)) * 2048 + 1024 + h * 64 + d];
        }
        __syncthreads();
#pragma unroll
        for (int s = 0; s < 4; s++) {
            int rr = w * 4 + s;
            float a = 0.f;
#pragma unroll
            for (int j2 = 0; j2 < 64; j2++) a += sc[rr][jt * 64 + j2] * ks[j2][jj];
            o1[s] += a;
        }
    }
#pragma unroll
    for (int s = 0; s < 4; s++) o1[s] /= rowsum[w * 4 + s];

    // ---------- attention 2: compressed k/v (len 128) ----------
    for (int jt = 0; jt < 2; jt++) {
        __syncthreads();
#pragma unroll
        for (int t = 0; t < 16; t++) {
            int e = tid + 256 * t; int j = e >> 6, d = e & 63;
            ks[j][d] = ckv[((long)(b * 128 + jt * 64 + j)) * 2048 + h * 64 + d];
        }
        __syncthreads();
#pragma unroll
        for (int s = 0; s < 4; s++) {
            int rr = w * 4 + s;
            float dot = 0.f;
#pragma unroll
            for (int d = 0; d < 64; d++) dot += qs[rr][d] * ks[jj][d];
            sc[rr][jt * 64 + jj] = dot * 0.125f;
        }
    }
    __syncthreads();
    {
        int row = tid >> 4, l = tid & 15;
        float mx = -3.4e38f;
        for (int c = l; c < 128; c += 16) mx = fmaxf(mx, sc[row][c]);
#pragma unroll
        for (int off = 8; off; off >>= 1) mx = fmaxf(mx, __shfl_xor(mx, off, 16));
        float sm = 0.f;
        for (int c = l; c < 128; c += 16) { float e = expf(sc[row][c] - mx); sc[row][c] = e; sm += e; }
#pragma unroll
        for (int off = 8; off; off >>= 1) sm += __shfl_xor(sm, off, 16);
        if (l == 0) rowsum[row] = sm;
    }
#pragma unroll
    for (int s = 0; s < 4; s++) o2[s] = 0.f;
    for (int jt = 0; jt < 2; jt++) {
        __syncthreads();
#pragma unroll
        for (int t = 0; t < 16; t++) {
            int e = tid + 256 * t; int j = e >> 6, d = e & 63;
            ks[j][d] = ckv[((long)(b * 128 + jt * 64 + j)) * 2048 + 1024 + h * 64 + d];
        }
        __syncthreads();
#pragma unroll
        for (int s = 0; s < 4; s++) {
            int rr = w * 4 + s;
            float a = 0.f;
#pragma unroll
            for (int j2 = 0; j2 < 64; j2++) a += sc[rr][jt * 64 + j2] * ks[j2][jj];
            o2[s] += a;
        }
    }
    __syncthreads();
#pragma unroll
    for (int s = 0; s < 4; s++) o2[s] /= rowsum[w * 4 + s];

    float local = 0.f;
#pragma unroll
    for (int s = 0; s < 4; s++) { float dd = o1[s] - o2[s]; local += dd * dd; }
#pragma unroll
    for (int off = 32; off; off >>= 1) local += __shfl_xor(local, off, 64);
    if ((tid & 63) == 0) wred[tid >> 6] = local;
    __syncthreads();
    if (tid == 0) partials[(long)blockIdx.y * 32 + blockIdx.x] = wred[0] + wred[1] + wred[2] + wred[3];
}

__global__ __launch_bounds__(256)
void aux_reduce_kernel(const float* __restrict__ partials, float* __restrict__ out)
{
    int tid = threadIdx.x;
    __shared__ float wred[4];
    float s = 0.f;
    for (int i = tid; i < 4096; i += 256) s += partials[i];
#pragma unroll
    for (int off = 32; off; off >>= 1) s += __shfl_xor(s, off, 64);
    if ((tid & 63) == 0) wred[tid >> 6] = s;
    __syncthreads();
    if (tid == 0) out[0] = (wred[0] + wred[1] + wred[2] + wred[3]) * (1.0f / 4194304.0f);
}

__global__ __launch_bounds__(256)
void copy_kernel(float* __restrict__ dst, const float* __restrict__ src, int n4)
{
    int i = blockIdx.x * 256 + threadIdx.x;
    int stride = gridDim.x * 256;
    for (; i < n4; i += stride)
        reinterpret_cast<float4*>(dst)[i] = reinterpret_cast<const float4*>(src)[i];
}

extern "C" void kernel_launch(void* const* d_in, const int* in_sizes, int n_in,
                              void* d_out, int out_size, void* d_ws, size_t ws_size,
                              hipStream_t stream)
{
    const float* x      = (const float*)d_in[0];
    const float* mem    = (const float*)d_in[1];
    const float* cmem   = (const float*)d_in[2];
    const float* pe     = (const float*)d_in[3];
    const float* Wq     = (const float*)d_in[4];
    const float* Wkv    = (const float*)d_in[5];
    const float* Wout   = (const float*)d_in[6];
    const float* bout   = (const float*)d_in[7];
    const float* conv_w = (const float*)d_in[8];
    const float* conv_b = (const float*)d_in[9];

    float* out_logits  = (float*)d_out;                 // 8*512*1024
    float* out_newmem  = out_logits + 4194304;          // 8*512*1024
    float* out_newcmem = out_newmem + 4194304;          // 8*128*1024
    float* out_aux     = out_newcmem + 1048576;         // 1
    float* out_weights = out_aux + 1;                   // 8*16*512*1152

    float* ws       = (float*)d_ws;
    float* q        = ws;                    // 4,194,304
    float* kvb      = q + 4194304;           // 18,874,368  (9216 x 2048: k | v)
    float* convwT   = kvb + 18874368;        // 4,194,304
    float* ckv      = convwT + 4194304;      // 2,097,152   (1024 x 2048)
    float* oat      = ckv + 2097152;         // 4,194,304   (attn out, (b,t,1024))
    float* partials = oat + 4194304;         // 4096

    dim3 blk(256);

    // q = x @ Wq                         (4096 x 1024 x 1024)
    gemm_kernel<<<dim3(16, 64, 1), blk, 0, stream>>>(
        x, Wq, q, 4096, 1024, 1024, 1024, 1024, 1024,
        0, 0, 0, 0, 0, 0, 1, nullptr, 0, nullptr, nullptr, nullptr);

    // kv = concat(cmem,mem,x) @ Wkv      (9216 x 1024 x 2048), gathered A
    gemm_kernel<<<dim3(32, 144, 1), blk, 0, stream>>>(
        x /*dummy*/, Wkv, kvb, 9216, 2048, 1024, 0, 2048, 2048,
        0, 0, 0, 0, 0, 0, 1, nullptr, 1, cmem, mem, x);

    // conv_w transpose -> (4096 x 1024)
    transpose_convw<<<dim3(4096), blk, 0, stream>>>(conv_w, convwT);

    // new_cmem = mem(1024x4096) @ convwT + conv_b   (1024 x 4096 x 1024)
    gemm_kernel<<<dim3(16, 16, 1), blk, 0, stream>>>(
        mem, convwT, out_newcmem, 1024, 1024, 4096, 4096, 1024, 1024,
        0, 0, 0, 0, 0, 0, 1, conv_b, 0, nullptr, nullptr, nullptr);

    // ckv = new_cmem @ Wkv               (1024 x 1024 x 2048)
    gemm_kernel<<<dim3(32, 16, 1), blk, 0, stream>>>(
        out_newcmem, Wkv, ckv, 1024, 2048, 1024, 1024, 2048, 2048,
        0, 0, 0, 0, 0, 0, 1, nullptr, 0, nullptr, nullptr, nullptr);

    // dots (+relative pos, shifted) -> weights region (pre-softmax)
    dots_kernel<<<dim3(36, 16, 128), blk, 0, stream>>>(q, kvb, pe, out_weights);

    // softmax in place -> weights output
    softmax_kernel<<<dim3(65536), blk, 0, stream>>>(out_weights);

    // attn @ v -> oat  (batched over 128 (b,h); M=512,N=64,K=1152)
    gemm_kernel<<<dim3(1, 8, 128), blk, 0, stream>>>(
        out_weights, kvb + 1024, oat, 512, 64, 1152, 1152, 2048, 1024,
        (long)16 * 589824, 589824, (long)1152 * 2048, 64, (long)512 * 1024, 64,
        16, nullptr, 0, nullptr, nullptr, nullptr);

    // logits = oat @ Wout + bout         (4096 x 1024 x 1024)
    gemm_kernel<<<dim3(16, 64, 1), blk, 0, stream>>>(
        oat, Wout, out_logits, 4096, 1024, 1024, 1024, 1024, 1024,
        0, 0, 0, 0, 0, 0, 1, bout, 0, nullptr, nullptr, nullptr);

    // new_mem = x
    copy_kernel<<<dim3(4096), blk, 0, stream>>>(out_newmem, x, 1048576);

    // aux loss
    aux_attn_kernel<<<dim3(32, 128), blk, 0, stream>>>(q, kvb, ckv, partials);
    aux_reduce_kernel<<<dim3(1), blk, 0, stream>>>(partials, out_aux);
}

// Round 2
// 3314.347 us; speedup vs baseline: 1.9532x; 1.9532x over previous
//
#include <hip/hip_runtime.h>
#include <cstdint>

// HEADS=16, DIM=1024, SEQ=512, MEM=512, CMEM=128, RATIO=4, DIM_H=64, b=8, kv_len=1152

typedef __bf16 bf16;
typedef __bf16 bf16x4 __attribute__((ext_vector_type(4)));
typedef __bf16 bf16x8 __attribute__((ext_vector_type(8)));
typedef float  f32x4  __attribute__((ext_vector_type(4)));

// ---------------------------------------------------------------------------
// MFMA GEMM: C[M,N] = A[M,K] @ B[K,N], tile 128x128, BK=32, 4 waves.
// A: fp32 row-major (AMODE0) or concat-gather rows of cmem/mem/x (AMODE1).
// B: BT layout [N][K]: fp32 (BMODE1) or bf16 (BMODE2).
// EPI: 0 normal(+bias), 1 P-rot scatter (*0.125), 2 qk + Prot add (*0.125),
//      3 kv: fp32 C + bf16 vT secondary for cols>=1024.
// Batched: z -> (zb=z/16, zh=z%16). M must be multiple of 128 (all our shapes).
// ---------------------------------------------------------------------------
template<int AMODE, int BMODE, int EPI>
__global__ __launch_bounds__(256)
void mfma_gemm(const float* __restrict__ A, const float* __restrict__ B1,
               const bf16* __restrict__ B2, float* __restrict__ C, bf16* __restrict__ vT,
               int N, int K, int lda, int ldbt, int ldc,
               long a_s0, long a_s1, long b_s0, long b_s1, long c_s0, long c_s1,
               const float* __restrict__ bias,
               const float* __restrict__ gcmem, const float* __restrict__ gmem,
               const float* __restrict__ gx)
{
    int z = blockIdx.z;
    int zb = z >> 4, zh = z & 15;
    const float* Ab  = A  ? (A  + zb * a_s0 + zh * a_s1) : nullptr;
    const float* Bb1 = B1 ? (B1 + zb * b_s0 + zh * b_s1) : nullptr;
    const bf16*  Bb2 = B2 ? (B2 + zb * b_s0 + zh * b_s1) : nullptr;
    float* Cb = C + zb * c_s0 + zh * c_s1;

    int row0 = blockIdx.y * 128, col0 = blockIdx.x * 128;
    int tid = threadIdx.x;

    __shared__ bf16 As[128][72];
    __shared__ bf16 Bs[128][72];

    // ---- staging address setup (hoisted out of K loop) ----
    int r_ = tid >> 3;            // 0..31
    int c4 = (tid & 7) * 4;       // A/B1 k-chunk (floats)
    const float* aptr[4];
#pragma unroll
    for (int jj = 0; jj < 4; jj++) {
        int gr = row0 + r_ + 32 * jj;
        if (AMODE == 0) {
            aptr[jj] = Ab + (long)gr * lda;
        } else {
            int bb = gr / 1152, rr = gr - bb * 1152;
            aptr[jj] = (rr < 128) ? (gcmem + ((long)bb * 128 + rr) * 1024)
                     : (rr < 640) ? (gmem + ((long)bb * 512 + (rr - 128)) * 1024)
                                  : (gx   + ((long)bb * 512 + (rr - 640)) * 1024);
        }
    }
    const float* bptr1[4];
    const bf16*  bptr2[2];
    int rn_ = tid >> 2;           // 0..63
    int c8  = (tid & 3) * 8;      // B2 k-chunk (bf16)
    if (BMODE == 1) {
#pragma unroll
        for (int jj = 0; jj < 4; jj++)
            bptr1[jj] = Bb1 + (long)(col0 + r_ + 32 * jj) * ldbt;
    } else {
#pragma unroll
        for (int jj = 0; jj < 2; jj++) {
            int gc = col0 + rn_ + 64 * jj;
            bptr2[jj] = (gc < N) ? (Bb2 + (long)gc * ldbt + c8) : nullptr;
        }
    }

    int lane = tid & 63, wid = tid >> 6;
    int wr = wid >> 1, wc = wid & 1;
    int fr = lane & 15, fq = lane >> 4;   // fragment row / quad

    f32x4 acc[4][4];
#pragma unroll
    for (int i = 0; i < 4; i++)
#pragma unroll
        for (int j = 0; j < 4; j++) acc[i][j] = (f32x4){0.f, 0.f, 0.f, 0.f};

    for (int k0 = 0; k0 < K; k0 += 32) {
        // stage A
#pragma unroll
        for (int jj = 0; jj < 4; jj++) {
            float4 f = *(const float4*)(aptr[jj] + k0 + c4);
            bf16x4 h = { (bf16)f.x, (bf16)f.y, (bf16)f.z, (bf16)f.w };
            *(bf16x4*)&As[r_ + 32 * jj][c4] = h;
        }
        // stage B
        if (BMODE == 1) {
#pragma unroll
            for (int jj = 0; jj < 4; jj++) {
                float4 f = *(const float4*)(bptr1[jj] + k0 + c4);
                bf16x4 h = { (bf16)f.x, (bf16)f.y, (bf16)f.z, (bf16)f.w };
                *(bf16x4*)&Bs[r_ + 32 * jj][c4] = h;
            }
        } else {
#pragma unroll
            for (int jj = 0; jj < 2; jj++) {
                bf16x8 v = {};
                if (bptr2[jj]) v = *(const bf16x8*)(bptr2[jj] + k0);
                *(bf16x8*)&Bs[rn_ + 64 * jj][c8] = v;
            }
        }
        __syncthreads();

        bf16x8 af[4], bfv[4];
#pragma unroll
        for (int i = 0; i < 4; i++)
            af[i] = *(const bf16x8*)&As[wr * 64 + i * 16 + fr][fq * 8];
#pragma unroll
        for (int j = 0; j < 4; j++)
            bfv[j] = *(const bf16x8*)&Bs[wc * 64 + j * 16 + fr][fq * 8];
#pragma unroll
        for (int i = 0; i < 4; i++)
#pragma unroll
            for (int j = 0; j < 4; j++)
                acc[i][j] = __builtin_amdgcn_mfma_f32_16x16x32_bf16(af[i], bfv[j], acc[i][j], 0, 0, 0);
        __syncthreads();
    }

    // ---- epilogue ----
#pragma unroll
    for (int i = 0; i < 4; i++) {
#pragma unroll
        for (int j = 0; j < 4; j++) {
#pragma unroll
            for (int g = 0; g < 4; g++) {
                int r = row0 + wr * 64 + i * 16 + fq * 4 + g;
                int c = col0 + wc * 64 + j * 16 + fr;
                float v = acc[i][j][g];
                if (EPI == 0) {
                    if (c < N) {
                        if (bias) v += bias[c];
                        Cb[(long)r * ldc + c] = v;
                    }
                } else if (EPI == 1) {
                    int cc = c + r - 511;
                    if (cc >= 0) Cb[(long)r * ldc + cc] = 0.125f * v;
                } else if (EPI == 2) {
                    float prev = (c < r + 641) ? Cb[(long)r * ldc + c] : 0.f;
                    Cb[(long)r * ldc + c] = 0.125f * v + prev;
                } else { // EPI == 3
                    Cb[(long)r * ldc + c] = v;
                    if (c >= 1024) {
                        int d = c - 1024; int hh = d >> 6; d &= 63;
                        int bb = r / 1152; int j2 = r - bb * 1152;
                        vT[(((long)(bb * 16 + hh)) * 64 + d) * 1152 + j2] = (bf16)v;
                    }
                }
            }
        }
    }
}

// fp32 [R][C] -> bf16 [C][R]
__global__ __launch_bounds__(256)
void transpose_cast(const float* __restrict__ in, bf16* __restrict__ out, int R, int C)
{
    __shared__ float t[32][33];
    int c0 = blockIdx.x * 32, r0 = blockIdx.y * 32;
    int tx = threadIdx.x & 31, ty = threadIdx.x >> 5;
#pragma unroll
    for (int i = 0; i < 32; i += 8)
        t[ty + i][tx] = in[(long)(r0 + ty + i) * C + c0 + tx];
    __syncthreads();
#pragma unroll
    for (int i = 0; i < 32; i += 8)
        out[(long)(c0 + ty + i) * R + r0 + tx] = (bf16)t[tx][ty + i];
}

// conv_w [o][i][r] -> bf16 [o][r*1024+i]
__global__ __launch_bounds__(256)
void convw_cast(const float* __restrict__ cw, bf16* __restrict__ out)
{
    long o = blockIdx.x;
    const float* src = cw + o * 4096;
    bf16* dst = out + o * 4096;
    for (int d = threadIdx.x; d < 4096; d += 256)
        dst[d] = (bf16)src[((d & 1023) << 2) | (d >> 10)];
}

// row softmax over 1152, in place
__global__ __launch_bounds__(256)
void softmax_kernel(float* __restrict__ W)
{
    long row = blockIdx.x;
    float* p = W + row * 1152;
    __shared__ float buf[1152];
    __shared__ float red[5];
    int tid = threadIdx.x;

    float mx = -3.4e38f;
    for (int c = tid; c < 1152; c += 256) { float v = p[c]; buf[c] = v; mx = fmaxf(mx, v); }
#pragma unroll
    for (int off = 32; off; off >>= 1) mx = fmaxf(mx, __shfl_xor(mx, off, 64));
    if ((tid & 63) == 0) red[tid >> 6] = mx;
    __syncthreads();
    if (tid == 0) red[4] = fmaxf(fmaxf(red[0], red[1]), fmaxf(red[2], red[3]));
    __syncthreads();
    float M = red[4];
    __syncthreads();

    float sm = 0.f;
    for (int c = tid; c < 1152; c += 256) { float e = expf(buf[c] - M); buf[c] = e; sm += e; }
#pragma unroll
    for (int off = 32; off; off >>= 1) sm += __shfl_xor(sm, off, 64);
    if ((tid & 63) == 0) red[tid >> 6] = sm;
    __syncthreads();
    if (tid == 0) red[4] = red[0] + red[1] + red[2] + red[3];
    __syncthreads();
    float inv = 1.f / red[4];
    for (int c = tid; c < 1152; c += 256) p[c] = buf[c] * inv;
}

// fused aux loss (fp32, unchanged from verified round-1 version)
__global__ __launch_bounds__(256)
void aux_attn_kernel(const float* __restrict__ q, const float* __restrict__ kv,
                     const float* __restrict__ ckv, float* __restrict__ partials)
{
    int z = blockIdx.y;
    int b = z >> 4, h = z & 15;
    int r0 = blockIdx.x * 16;
    int tid = threadIdx.x;

    __shared__ float qs[16][65];
    __shared__ float ks[64][65];
    __shared__ float sc[16][512];
    __shared__ float rowsum[16];
    __shared__ float wred[4];

#pragma unroll
    for (int t = 0; t < 4; t++) {
        int e = tid + 256 * t; int rr = e >> 6, d = e & 63;
        qs[rr][d] = q[((long)(b * 512 + r0 + rr)) * 1024 + h * 64 + d];
    }

    float o1[4], o2[4];
    int jj = tid & 63, w = tid >> 6;

    for (int jt = 0; jt < 8; jt++) {
        __syncthreads();
#pragma unroll
        for (int t = 0; t < 16; t++) {
            int e = tid + 256 * t; int j = e >> 6, d = e & 63;
            ks[j][d] = kv[((long)(b * 1152 + 128 + jt * 64 + j)) * 2048 + h * 64 + d];
        }
        __syncthreads();
#pragma unroll
        for (int s = 0; s < 4; s++) {
            int rr = w * 4 + s;
            float dot = 0.f;
#pragma unroll
            for (int d = 0; d < 64; d++) dot += qs[rr][d] * ks[jj][d];
            sc[rr][jt * 64 + jj] = dot * 0.125f;
        }
    }
    __syncthreads();
    {
        int row = tid >> 4, l = tid & 15;
        float mx = -3.4e38f;
        for (int c = l; c < 512; c += 16) mx = fmaxf(mx, sc[row][c]);
#pragma unroll
        for (int off = 8; off; off >>= 1) mx = fmaxf(mx, __shfl_xor(mx, off, 16));
        float sm = 0.f;
        for (int c = l; c < 512; c += 16) { float e = expf(sc[row][c] - mx); sc[row][c] = e; sm += e; }
#pragma unroll
        for (int off = 8; off; off >>= 1) sm += __shfl_xor(sm, off, 16);
        if (l == 0) rowsum[row] = sm;
    }
#pragma unroll
    for (int s = 0; s < 4; s++) o1[s] = 0.f;
    for (int jt = 0; jt < 8; jt++) {
        __syncthreads();
#pragma unroll
        for (int t = 0; t < 16; t++) {
            int e = tid + 256 * t; int j = e >> 6, d = e & 63;
            ks[j][d] = kv[((long)(b * 1152 + 128 + jt * 64 + j)) * 2048 + 1024 + h * 64 + d];
        }
        __syncthreads();
#pragma unroll
        for (int s = 0; s < 4; s++) {
            int rr = w * 4 + s;
            float a = 0.f;
#pragma unroll
            for (int j2 = 0; j2 < 64; j2++) a += sc[rr][jt * 64 + j2] * ks[j2][jj];
            o1[s] += a;
        }
    }
#pragma unroll
    for (int s = 0; s < 4; s++) o1[s] /= rowsum[w * 4 + s];

    for (int jt = 0; jt < 2; jt++) {
        __syncthreads();
#pragma unroll
        for (int t = 0; t < 16; t++) {
            int e = tid + 256 * t; int j = e >> 6, d = e & 63;
            ks[j][d] = ckv[((long)(b * 128 + jt * 64 + j)) * 2048 + h * 64 + d];
        }
        __syncthreads();
#pragma unroll
        for (int s = 0; s < 4; s++) {
            int rr = w * 4 + s;
            float dot = 0.f;
#pragma unroll
            for (int d = 0; d < 64; d++) dot += qs[rr][d] * ks[jj][d];
            sc[rr][jt * 64 + jj] = dot * 0.125f;
        }
    }
    __syncthreads();
    {
        int row = tid >> 4, l = tid & 15;
        float mx = -3.4e38f;
        for (int c = l; c < 128; c += 16) mx = fmaxf(mx, sc[row][c]);
#pragma unroll
        for (int off = 8; off; off >>= 1) mx = fmaxf(mx, __shfl_xor(mx, off, 16));
        float sm = 0.f;
        for (int c = l; c < 128; c += 16) { float e = expf(sc[row][c] - mx); sc[row][c] = e; sm += e; }
#pragma unroll
        for (int off = 8; off; off >>= 1) sm += __shfl_xor(sm, off, 16);
        if (l == 0) rowsum[row] = sm;
    }
#pragma unroll
    for (int s = 0; s < 4; s++) o2[s] = 0.f;
    for (int jt = 0; jt < 2; jt++) {
        __syncthreads();
#pragma unroll
        for (int t = 0; t < 16; t++) {
            int e = tid + 256 * t; int j = e >> 6, d = e & 63;
            ks[j][d] = ckv[((long)(b * 128 + jt * 64 + j)) * 2048 + 1024 + h * 64 + d];
        }
        __syncthreads();
#pragma unroll
        for (int s = 0; s < 4; s++) {
            int rr = w * 4 + s;
            float a = 0.f;
#pragma unroll
            for (int j2 = 0; j2 < 64; j2++) a += sc[rr][jt * 64 + j2] * ks[j2][jj];
            o2[s] += a;
        }
    }
    __syncthreads();
#pragma unroll
    for (int s = 0; s < 4; s++) o2[s] /= rowsum[w * 4 + s];

    float local = 0.f;
#pragma unroll
    for (int s = 0; s < 4; s++) { float dd = o1[s] - o2[s]; local += dd * dd; }
#pragma unroll
    for (int off = 32; off; off >>= 1) local += __shfl_xor(local, off, 64);
    if ((tid & 63) == 0) wred[tid >> 6] = local;
    __syncthreads();
    if (tid == 0) partials[(long)blockIdx.y * 32 + blockIdx.x] = wred[0] + wred[1] + wred[2] + wred[3];
}

__global__ __launch_bounds__(256)
void aux_reduce_kernel(const float* __restrict__ partials, float* __restrict__ out)
{
    int tid = threadIdx.x;
    __shared__ float wred[4];
    float s = 0.f;
    for (int i = tid; i < 4096; i += 256) s += partials[i];
#pragma unroll
    for (int off = 32; off; off >>= 1) s += __shfl_xor(s, off, 64);
    if ((tid & 63) == 0) wred[tid >> 6] = s;
    __syncthreads();
    if (tid == 0) out[0] = (wred[0] + wred[1] + wred[2] + wred[3]) * (1.0f / 4194304.0f);
}

__global__ __launch_bounds__(256)
void copy_kernel(float* __restrict__ dst, const float* __restrict__ src, int n4)
{
    int i = blockIdx.x * 256 + threadIdx.x;
    int stride = gridDim.x * 256;
    for (; i < n4; i += stride)
        reinterpret_cast<float4*>(dst)[i] = reinterpret_cast<const float4*>(src)[i];
}

extern "C" void kernel_launch(void* const* d_in, const int* in_sizes, int n_in,
                              void* d_out, int out_size, void* d_ws, size_t ws_size,
                              hipStream_t stream)
{
    const float* x      = (const float*)d_in[0];
    const float* mem    = (const float*)d_in[1];
    const float* cmem   = (const float*)d_in[2];
    const float* pe     = (const float*)d_in[3];
    const float* Wq     = (const float*)d_in[4];
    const float* Wkv    = (const float*)d_in[5];
    const float* Wout   = (const float*)d_in[6];
    const float* bout   = (const float*)d_in[7];
    const float* conv_w = (const float*)d_in[8];
    const float* conv_b = (const float*)d_in[9];

    float* out_logits  = (float*)d_out;                 // 8*512*1024
    float* out_newmem  = out_logits + 4194304;          // 8*512*1024
    float* out_newcmem = out_newmem + 4194304;          // 8*128*1024
    float* out_aux     = out_newcmem + 1048576;         // 1
    float* out_weights = out_aux + 1;                   // 8*16*512*1152

    // workspace layout
    float* ws       = (float*)d_ws;
    float* q        = ws;                    // 4,194,304 f
    float* kvb      = q + 4194304;           // 18,874,368 f
    float* ckv      = kvb + 18874368;        // 2,097,152 f
    float* oat      = ckv + 2097152;         // 4,194,304 f
    float* partials = oat + 4194304;         // 4096 f
    bf16* bws      = (bf16*)(partials + 4096);
    bf16* WqTb     = bws;                    // 1,048,576
    bf16* WkvTb    = WqTb + 1048576;         // 2,097,152
    bf16* WoutTb   = WkvTb + 2097152;        // 1,048,576
    bf16* convwTb  = WoutTb + 1048576;       // 4,194,304
    bf16* vTb      = convwTb + 4194304;      // 9,437,184

    dim3 blk(256);

    // weight transposes/casts
    transpose_cast<<<dim3(32, 32), blk, 0, stream>>>(Wq, WqTb, 1024, 1024);
    transpose_cast<<<dim3(64, 32), blk, 0, stream>>>(Wkv, WkvTb, 1024, 2048);
    transpose_cast<<<dim3(32, 32), blk, 0, stream>>>(Wout, WoutTb, 1024, 1024);
    convw_cast<<<dim3(1024), blk, 0, stream>>>(conv_w, convwTb);

    // q = x @ Wq     (4096 x 1024 x 1024)
    mfma_gemm<0, 2, 0><<<dim3(8, 32, 1), blk, 0, stream>>>(
        x, nullptr, WqTb, q, nullptr, 1024, 1024, 1024, 1024, 1024,
        0, 0, 0, 0, 0, 0, nullptr, nullptr, nullptr, nullptr);

    // kv = concat(cmem,mem,x) @ Wkv  (9216 x 1024 x 2048) + vT bf16 secondary
    mfma_gemm<1, 2, 3><<<dim3(16, 72, 1), blk, 0, stream>>>(
        nullptr, nullptr, WkvTb, kvb, vTb, 2048, 1024, 1024, 1024, 2048,
        0, 0, 0, 0, 0, 0, nullptr, cmem, mem, x);

    // new_cmem = mem[1024x4096] @ convwT + conv_b  (1024 x 4096 x 1024)
    mfma_gemm<0, 2, 0><<<dim3(8, 8, 1), blk, 0, stream>>>(
        mem, nullptr, convwTb, out_newcmem, nullptr, 1024, 4096, 4096, 4096, 1024,
        0, 0, 0, 0, 0, 0, conv_b, nullptr, nullptr, nullptr);

    // ckv = new_cmem @ Wkv   (1024 x 1024 x 2048)
    mfma_gemm<0, 2, 0><<<dim3(16, 8, 1), blk, 0, stream>>>(
        out_newcmem, nullptr, WkvTb, ckv, nullptr, 2048, 1024, 1024, 1024, 2048,
        0, 0, 0, 0, 0, 0, nullptr, nullptr, nullptr, nullptr);

    // P = q @ pe^T -> rotated scatter into out_weights  (z=128: M=512,N=1152,K=64)
    mfma_gemm<0, 1, 1><<<dim3(9, 4, 128), blk, 0, stream>>>(
        q, pe, nullptr, out_weights, nullptr, 1152, 64, 1024, 64, 1152,
        524288, 64, 0, 73728, (long)16 * 589824, 589824, nullptr, nullptr, nullptr, nullptr);

    // dots = 0.125*q@k^T + Prot -> out_weights (pre-softmax)
    mfma_gemm<0, 1, 2><<<dim3(9, 4, 128), blk, 0, stream>>>(
        q, kvb, nullptr, out_weights, nullptr, 1152, 64, 1024, 2048, 1152,
        524288, 64, (long)1152 * 2048, 64, (long)16 * 589824, 589824, nullptr, nullptr, nullptr, nullptr);

    // softmax in place
    softmax_kernel<<<dim3(65536), blk, 0, stream>>>(out_weights);

    // out = attn @ v -> oat  (z=128: M=512,N=64,K=1152), B = vTb bf16
    mfma_gemm<0, 2, 0><<<dim3(1, 4, 128), blk, 0, stream>>>(
        out_weights, nullptr, vTb, oat, nullptr, 64, 1152, 1152, 1152, 1024,
        (long)16 * 589824, 589824, (long)16 * 64 * 1152, (long)64 * 1152, 524288, 64,
        nullptr, nullptr, nullptr, nullptr);

    // logits = oat @ Wout + bout  (4096 x 1024 x 1024)
    mfma_gemm<0, 2, 0><<<dim3(8, 32, 1), blk, 0, stream>>>(
        oat, nullptr, WoutTb, out_logits, nullptr, 1024, 1024, 1024, 1024, 1024,
        0, 0, 0, 0, 0, 0, bout, nullptr, nullptr, nullptr);

    // new_mem = x
    copy_kernel<<<dim3(4096), blk, 0, stream>>>(out_newmem, x, 1048576);

    // aux loss (fp32)
    aux_attn_kernel<<<dim3(32, 128), blk, 0, stream>>>(q, kvb, ckv, partials);
    aux_reduce_kernel<<<dim3(1), blk, 0, stream>>>(partials, out_aux);
}

// Round 3
// 1420.123 us; speedup vs baseline: 4.5584x; 2.3338x over previous
//
#include <hip/hip_runtime.h>
#include <cstdint>

// HEADS=16, DIM=1024, SEQ=512, MEM=512, CMEM=128, RATIO=4, DIM_H=64, b=8, kv_len=1152

typedef __bf16 bf16;
typedef __bf16 bf16x4 __attribute__((ext_vector_type(4)));
typedef __bf16 bf16x8 __attribute__((ext_vector_type(8)));
typedef float  f32x4  __attribute__((ext_vector_type(4)));

// ---------------------------------------------------------------------------
// MFMA GEMM: C[M,N] = A[M,K] @ B[K,N], tile 128x128, BK=32, 4 waves.
// A: fp32 row-major (AMODE0) or concat-gather rows of cmem/mem/x (AMODE1).
// B: BT layout [N][K]: fp32 (BMODE1) or bf16 (BMODE2).
// EPI: 0 normal(+bias), 1 P-rot scatter (*0.125), 2 qk + Prot add (*0.125),
//      3 fp32 C + bf16 vT secondary for cols>=1024 (row modulus vrows).
// ---------------------------------------------------------------------------
template<int AMODE, int BMODE, int EPI>
__global__ __launch_bounds__(256)
void mfma_gemm(const float* __restrict__ A, const float* __restrict__ B1,
               const bf16* __restrict__ B2, float* __restrict__ C, bf16* __restrict__ vT,
               int N, int K, int lda, int ldbt, int ldc,
               long a_s0, long a_s1, long b_s0, long b_s1, long c_s0, long c_s1,
               const float* __restrict__ bias, int vrows,
               const float* __restrict__ gcmem, const float* __restrict__ gmem,
               const float* __restrict__ gx)
{
    int z = blockIdx.z;
    int zb = z >> 4, zh = z & 15;
    const float* Ab  = A  ? (A  + zb * a_s0 + zh * a_s1) : nullptr;
    const float* Bb1 = B1 ? (B1 + zb * b_s0 + zh * b_s1) : nullptr;
    const bf16*  Bb2 = B2 ? (B2 + zb * b_s0 + zh * b_s1) : nullptr;
    float* Cb = C + zb * c_s0 + zh * c_s1;

    int row0 = blockIdx.y * 128, col0 = blockIdx.x * 128;
    int tid = threadIdx.x;

    __shared__ bf16 As[128][72];
    __shared__ bf16 Bs[128][72];

    int r_ = tid >> 3;            // 0..31
    int c4 = (tid & 7) * 4;       // A/B1 k-chunk (floats)
    const float* aptr[4];
#pragma unroll
    for (int jj = 0; jj < 4; jj++) {
        int gr = row0 + r_ + 32 * jj;
        if (AMODE == 0) {
            aptr[jj] = Ab + (long)gr * lda;
        } else {
            int bb = gr / 1152, rr = gr - bb * 1152;
            aptr[jj] = (rr < 128) ? (gcmem + ((long)bb * 128 + rr) * 1024)
                     : (rr < 640) ? (gmem + ((long)bb * 512 + (rr - 128)) * 1024)
                                  : (gx   + ((long)bb * 512 + (rr - 640)) * 1024);
        }
    }
    const float* bptr1[4];
    const bf16*  bptr2[2];
    int rn_ = tid >> 2;           // 0..63
    int c8  = (tid & 3) * 8;      // B2 k-chunk (bf16)
    if (BMODE == 1) {
#pragma unroll
        for (int jj = 0; jj < 4; jj++)
            bptr1[jj] = Bb1 + (long)(col0 + r_ + 32 * jj) * ldbt;
    } else {
#pragma unroll
        for (int jj = 0; jj < 2; jj++) {
            int gc = col0 + rn_ + 64 * jj;
            bptr2[jj] = (gc < N) ? (Bb2 + (long)gc * ldbt + c8) : nullptr;
        }
    }

    int lane = tid & 63, wid = tid >> 6;
    int wr = wid >> 1, wc = wid & 1;
    int fr = lane & 15, fq = lane >> 4;

    f32x4 acc[4][4];
#pragma unroll
    for (int i = 0; i < 4; i++)
#pragma unroll
        for (int j = 0; j < 4; j++) acc[i][j] = (f32x4){0.f, 0.f, 0.f, 0.f};

    for (int k0 = 0; k0 < K; k0 += 32) {
#pragma unroll
        for (int jj = 0; jj < 4; jj++) {
            float4 f = *(const float4*)(aptr[jj] + k0 + c4);
            bf16x4 h = { (bf16)f.x, (bf16)f.y, (bf16)f.z, (bf16)f.w };
            *(bf16x4*)&As[r_ + 32 * jj][c4] = h;
        }
        if (BMODE == 1) {
#pragma unroll
            for (int jj = 0; jj < 4; jj++) {
                float4 f = *(const float4*)(bptr1[jj] + k0 + c4);
                bf16x4 h = { (bf16)f.x, (bf16)f.y, (bf16)f.z, (bf16)f.w };
                *(bf16x4*)&Bs[r_ + 32 * jj][c4] = h;
            }
        } else {
#pragma unroll
            for (int jj = 0; jj < 2; jj++) {
                bf16x8 v = {};
                if (bptr2[jj]) v = *(const bf16x8*)(bptr2[jj] + k0);
                *(bf16x8*)&Bs[rn_ + 64 * jj][c8] = v;
            }
        }
        __syncthreads();

        bf16x8 af[4], bfv[4];
#pragma unroll
        for (int i = 0; i < 4; i++)
            af[i] = *(const bf16x8*)&As[wr * 64 + i * 16 + fr][fq * 8];
#pragma unroll
        for (int j = 0; j < 4; j++)
            bfv[j] = *(const bf16x8*)&Bs[wc * 64 + j * 16 + fr][fq * 8];
#pragma unroll
        for (int i = 0; i < 4; i++)
#pragma unroll
            for (int j = 0; j < 4; j++)
                acc[i][j] = __builtin_amdgcn_mfma_f32_16x16x32_bf16(af[i], bfv[j], acc[i][j], 0, 0, 0);
        __syncthreads();
    }

#pragma unroll
    for (int i = 0; i < 4; i++) {
#pragma unroll
        for (int j = 0; j < 4; j++) {
#pragma unroll
            for (int g = 0; g < 4; g++) {
                int r = row0 + wr * 64 + i * 16 + fq * 4 + g;
                int c = col0 + wc * 64 + j * 16 + fr;
                float v = acc[i][j][g];
                if (EPI == 0) {
                    if (c < N) {
                        if (bias) v += bias[c];
                        Cb[(long)r * ldc + c] = v;
                    }
                } else if (EPI == 1) {
                    int cc = c + r - 511;
                    if (cc >= 0) Cb[(long)r * ldc + cc] = 0.125f * v;
                } else if (EPI == 2) {
                    float prev = (c < r + 641) ? Cb[(long)r * ldc + c] : 0.f;
                    Cb[(long)r * ldc + c] = 0.125f * v + prev;
                } else { // EPI == 3
                    Cb[(long)r * ldc + c] = v;
                    if (c >= 1024) {
                        int d = c - 1024; int hh = d >> 6; d &= 63;
                        int bb = r / vrows; int j2 = r - bb * vrows;
                        vT[(((long)(bb * 16 + hh)) * 64 + d) * vrows + j2] = (bf16)v;
                    }
                }
            }
        }
    }
}

// fp32 [R][C] -> bf16 [C][R]
__global__ __launch_bounds__(256)
void transpose_cast(const float* __restrict__ in, bf16* __restrict__ out, int R, int C)
{
    __shared__ float t[32][33];
    int c0 = blockIdx.x * 32, r0 = blockIdx.y * 32;
    int tx = threadIdx.x & 31, ty = threadIdx.x >> 5;
#pragma unroll
    for (int i = 0; i < 32; i += 8)
        t[ty + i][tx] = in[(long)(r0 + ty + i) * C + c0 + tx];
    __syncthreads();
#pragma unroll
    for (int i = 0; i < 32; i += 8)
        out[(long)(c0 + ty + i) * R + r0 + tx] = (bf16)t[tx][ty + i];
}

// conv_w [o][i][r] -> bf16 [o][r*1024+i]
__global__ __launch_bounds__(256)
void convw_cast(const float* __restrict__ cw, bf16* __restrict__ out)
{
    long o = blockIdx.x;
    const float* src = cw + o * 4096;
    bf16* dst = out + o * 4096;
    for (int d = threadIdx.x; d < 4096; d += 256)
        dst[d] = (bf16)src[((d & 1023) << 2) | (d >> 10)];
}

// row softmax over 1152, in place
__global__ __launch_bounds__(256)
void softmax_kernel(float* __restrict__ W)
{
    long row = blockIdx.x;
    float* p = W + row * 1152;
    __shared__ float buf[1152];
    __shared__ float red[5];
    int tid = threadIdx.x;

    float mx = -3.4e38f;
    for (int c = tid; c < 1152; c += 256) { float v = p[c]; buf[c] = v; mx = fmaxf(mx, v); }
#pragma unroll
    for (int off = 32; off; off >>= 1) mx = fmaxf(mx, __shfl_xor(mx, off, 64));
    if ((tid & 63) == 0) red[tid >> 6] = mx;
    __syncthreads();
    if (tid == 0) red[4] = fmaxf(fmaxf(red[0], red[1]), fmaxf(red[2], red[3]));
    __syncthreads();
    float M = red[4];
    __syncthreads();

    float sm = 0.f;
    for (int c = tid; c < 1152; c += 256) { float e = expf(buf[c] - M); buf[c] = e; sm += e; }
#pragma unroll
    for (int off = 32; off; off >>= 1) sm += __shfl_xor(sm, off, 64);
    if ((tid & 63) == 0) red[tid >> 6] = sm;
    __syncthreads();
    if (tid == 0) red[4] = red[0] + red[1] + red[2] + red[3];
    __syncthreads();
    float inv = 1.f / red[4];
    for (int c = tid; c < 1152; c += 256) p[c] = buf[c] * inv;
}

// ---------------------------------------------------------------------------
// Fused MFMA aux loss: per (b,h,128 q-rows): flash attn over mem k/v (512)
// and over compressed k/v (128); accumulate ||o1-o2||^2 per block.
// ---------------------------------------------------------------------------
__global__ __launch_bounds__(256)
void aux_mfma_kernel(const float* __restrict__ q, const float* __restrict__ kvb,
                     const float* __restrict__ ckv,
                     const bf16* __restrict__ vTb, const bf16* __restrict__ cvT,
                     float* __restrict__ partials)
{
    int z = blockIdx.y;                 // b*16 + h
    int b = z >> 4, h = z & 15;
    int r0 = blockIdx.x * 128;
    int tid = threadIdx.x;
    int lane = tid & 63, wid = tid >> 6;
    int fr = lane & 15, fq = lane >> 4;

    __shared__ bf16 qs[128][72];
    __shared__ bf16 upool[128 * 136];   // ks (stride 72) then pt (stride 136)
    __shared__ bf16 vt[64][136];
    __shared__ float wred[4];

    // stage q (128 x 64)
#pragma unroll
    for (int t = 0; t < 8; t++) {
        int e = tid + 256 * t; int rr = e >> 4, c4 = (e & 15) * 4;
        float4 f = *(const float4*)&q[((long)(b * 512 + r0 + rr)) * 1024 + h * 64 + c4];
        bf16x4 hv = { (bf16)f.x, (bf16)f.y, (bf16)f.z, (bf16)f.w };
        *(bf16x4*)&qs[rr][c4] = hv;
    }

    float o1[2][4][4];
    f32x4 oaccv[2][4];
    float mrow[2][4], lrow[2][4];
    f32x4 sacc[2][8];
    float local = 0.f;

    for (int pass = 0; pass < 2; pass++) {
#pragma unroll
        for (int i = 0; i < 2; i++)
#pragma unroll
            for (int g = 0; g < 4; g++) { mrow[i][g] = -3.4e38f; lrow[i][g] = 0.f; }
#pragma unroll
        for (int i = 0; i < 2; i++)
#pragma unroll
            for (int jd = 0; jd < 4; jd++) oaccv[i][jd] = (f32x4){0.f, 0.f, 0.f, 0.f};

        int nchunk = pass ? 1 : 4;
        for (int jt = 0; jt < nchunk; jt++) {
            __syncthreads();
            if (pass == 0) {
                long base = (long)(b * 1152 + 128 + jt * 128);
#pragma unroll
                for (int t = 0; t < 8; t++) {
                    int e = tid + 256 * t; int j = e >> 4, c4 = (e & 15) * 4;
                    float4 f = *(const float4*)&kvb[(base + j) * 2048 + h * 64 + c4];
                    bf16x4 hv = { (bf16)f.x, (bf16)f.y, (bf16)f.z, (bf16)f.w };
                    *(bf16x4*)&upool[j * 72 + c4] = hv;
                }
#pragma unroll
                for (int t = 0; t < 4; t++) {
                    int e = tid + 256 * t; int d = e >> 4, j8 = (e & 15) * 8;
                    *(bf16x8*)&vt[d][j8] =
                        *(const bf16x8*)&vTb[((long)z * 64 + d) * 1152 + 128 + jt * 128 + j8];
                }
            } else {
#pragma unroll
                for (int t = 0; t < 8; t++) {
                    int e = tid + 256 * t; int j = e >> 4, c4 = (e & 15) * 4;
                    float4 f = *(const float4*)&ckv[((long)(b * 128 + j)) * 2048 + h * 64 + c4];
                    bf16x4 hv = { (bf16)f.x, (bf16)f.y, (bf16)f.z, (bf16)f.w };
                    *(bf16x4*)&upool[j * 72 + c4] = hv;
                }
#pragma unroll
                for (int t = 0; t < 4; t++) {
                    int e = tid + 256 * t; int d = e >> 4, j8 = (e & 15) * 8;
                    *(bf16x8*)&vt[d][j8] = *(const bf16x8*)&cvT[((long)z * 64 + d) * 128 + j8];
                }
            }
            __syncthreads();

            // S = q @ k^T  (wave: 32 rows x 128 cols)
#pragma unroll
            for (int i = 0; i < 2; i++)
#pragma unroll
                for (int j = 0; j < 8; j++) sacc[i][j] = (f32x4){0.f, 0.f, 0.f, 0.f};
#pragma unroll
            for (int s = 0; s < 2; s++) {
                bf16x8 af[2], bfv[8];
#pragma unroll
                for (int i = 0; i < 2; i++)
                    af[i] = *(const bf16x8*)&qs[wid * 32 + i * 16 + fr][s * 32 + fq * 8];
#pragma unroll
                for (int j = 0; j < 8; j++)
                    bfv[j] = *(const bf16x8*)&upool[(j * 16 + fr) * 72 + s * 32 + fq * 8];
#pragma unroll
                for (int i = 0; i < 2; i++)
#pragma unroll
                    for (int j = 0; j < 8; j++)
                        sacc[i][j] = __builtin_amdgcn_mfma_f32_16x16x32_bf16(af[i], bfv[j], sacc[i][j], 0, 0, 0);
            }
            __syncthreads();   // all waves done reading ks before pt overwrite

            // online softmax + P -> LDS (bf16)
#pragma unroll
            for (int i = 0; i < 2; i++) {
#pragma unroll
                for (int g = 0; g < 4; g++) {
                    float mx = -3.4e38f;
#pragma unroll
                    for (int j = 0; j < 8; j++) mx = fmaxf(mx, sacc[i][j][g]);
                    mx *= 0.125f;
#pragma unroll
                    for (int msk = 1; msk <= 8; msk <<= 1) mx = fmaxf(mx, __shfl_xor(mx, msk, 64));
                    float mnew = fmaxf(mrow[i][g], mx);
                    float alpha = __expf(mrow[i][g] - mnew);
                    mrow[i][g] = mnew;
                    float sum = 0.f;
                    int prow = (wid * 32 + i * 16 + fq * 4 + g) * 136;
#pragma unroll
                    for (int j = 0; j < 8; j++) {
                        float p = __expf(sacc[i][j][g] * 0.125f - mnew);
                        sum += p;
                        upool[prow + j * 16 + fr] = (bf16)p;
                    }
#pragma unroll
                    for (int msk = 1; msk <= 8; msk <<= 1) sum += __shfl_xor(sum, msk, 64);
                    lrow[i][g] = lrow[i][g] * alpha + sum;
#pragma unroll
                    for (int jd = 0; jd < 4; jd++) oaccv[i][jd][g] *= alpha;
                }
            }
            __syncthreads();

            // PV
#pragma unroll
            for (int s2 = 0; s2 < 4; s2++) {
                bf16x8 pa[2], vb[4];
#pragma unroll
                for (int i = 0; i < 2; i++)
                    pa[i] = *(const bf16x8*)&upool[(wid * 32 + i * 16 + fr) * 136 + s2 * 32 + fq * 8];
#pragma unroll
                for (int jd = 0; jd < 4; jd++)
                    vb[jd] = *(const bf16x8*)&vt[jd * 16 + fr][s2 * 32 + fq * 8];
#pragma unroll
                for (int i = 0; i < 2; i++)
#pragma unroll
                    for (int jd = 0; jd < 4; jd++)
                        oaccv[i][jd] = __builtin_amdgcn_mfma_f32_16x16x32_bf16(pa[i], vb[jd], oaccv[i][jd], 0, 0, 0);
            }
        }

        if (pass == 0) {
#pragma unroll
            for (int i = 0; i < 2; i++)
#pragma unroll
                for (int jd = 0; jd < 4; jd++)
#pragma unroll
                    for (int g = 0; g < 4; g++)
                        o1[i][jd][g] = oaccv[i][jd][g] / lrow[i][g];
        } else {
#pragma unroll
            for (int i = 0; i < 2; i++)
#pragma unroll
                for (int jd = 0; jd < 4; jd++)
#pragma unroll
                    for (int g = 0; g < 4; g++) {
                        float dd = o1[i][jd][g] - oaccv[i][jd][g] / lrow[i][g];
                        local += dd * dd;
                    }
        }
    }

#pragma unroll
    for (int off = 32; off; off >>= 1) local += __shfl_xor(local, off, 64);
    if (lane == 0) wred[wid] = local;
    __syncthreads();
    if (tid == 0)
        partials[(long)blockIdx.y * 4 + blockIdx.x] = wred[0] + wred[1] + wred[2] + wred[3];
}

__global__ __launch_bounds__(256)
void aux_reduce_kernel(const float* __restrict__ partials, float* __restrict__ out)
{
    int tid = threadIdx.x;
    __shared__ float wred[4];
    float s = 0.f;
    for (int i = tid; i < 512; i += 256) s += partials[i];
#pragma unroll
    for (int off = 32; off; off >>= 1) s += __shfl_xor(s, off, 64);
    if ((tid & 63) == 0) wred[tid >> 6] = s;
    __syncthreads();
    if (tid == 0) out[0] = (wred[0] + wred[1] + wred[2] + wred[3]) * (1.0f / 4194304.0f);
}

__global__ __launch_bounds__(256)
void copy_kernel(float* __restrict__ dst, const float* __restrict__ src, int n4)
{
    int i = blockIdx.x * 256 + threadIdx.x;
    int stride = gridDim.x * 256;
    for (; i < n4; i += stride)
        reinterpret_cast<float4*>(dst)[i] = reinterpret_cast<const float4*>(src)[i];
}

extern "C" void kernel_launch(void* const* d_in, const int* in_sizes, int n_in,
                              void* d_out, int out_size, void* d_ws, size_t ws_size,
                              hipStream_t stream)
{
    const float* x      = (const float*)d_in[0];
    const float* mem    = (const float*)d_in[1];
    const float* cmem   = (const float*)d_in[2];
    const float* pe     = (const float*)d_in[3];
    const float* Wq     = (const float*)d_in[4];
    const float* Wkv    = (const float*)d_in[5];
    const float* Wout   = (const float*)d_in[6];
    const float* bout   = (const float*)d_in[7];
    const float* conv_w = (const float*)d_in[8];
    const float* conv_b = (const float*)d_in[9];

    float* out_logits  = (float*)d_out;                 // 8*512*1024
    float* out_newmem  = out_logits + 4194304;          // 8*512*1024
    float* out_newcmem = out_newmem + 4194304;          // 8*128*1024
    float* out_aux     = out_newcmem + 1048576;         // 1
    float* out_weights = out_aux + 1;                   // 8*16*512*1152

    // workspace layout
    float* ws       = (float*)d_ws;
    float* q        = ws;                    // 4,194,304 f
    float* kvb      = q + 4194304;           // 18,874,368 f
    float* ckv      = kvb + 18874368;        // 2,097,152 f
    float* oat      = ckv + 2097152;         // 4,194,304 f
    float* partials = oat + 4194304;         // 512 f (pad to 4096)
    bf16* bws      = (bf16*)(partials + 4096);
    bf16* WqTb     = bws;                    // 1,048,576
    bf16* WkvTb    = WqTb + 1048576;         // 2,097,152
    bf16* WoutTb   = WkvTb + 2097152;        // 1,048,576
    bf16* convwTb  = WoutTb + 1048576;       // 4,194,304
    bf16* vTb      = convwTb + 4194304;      // 9,437,184
    bf16* cvT      = vTb + 9437184;          // 1,048,576

    dim3 blk(256);

    // weight transposes/casts
    transpose_cast<<<dim3(32, 32), blk, 0, stream>>>(Wq, WqTb, 1024, 1024);
    transpose_cast<<<dim3(64, 32), blk, 0, stream>>>(Wkv, WkvTb, 1024, 2048);
    transpose_cast<<<dim3(32, 32), blk, 0, stream>>>(Wout, WoutTb, 1024, 1024);
    convw_cast<<<dim3(1024), blk, 0, stream>>>(conv_w, convwTb);

    // q = x @ Wq     (4096 x 1024 x 1024)
    mfma_gemm<0, 2, 0><<<dim3(8, 32, 1), blk, 0, stream>>>(
        x, nullptr, WqTb, q, nullptr, 1024, 1024, 1024, 1024, 1024,
        0, 0, 0, 0, 0, 0, nullptr, 0, nullptr, nullptr, nullptr);

    // kv = concat(cmem,mem,x) @ Wkv  (9216 x 1024 x 2048) + vT bf16 secondary
    mfma_gemm<1, 2, 3><<<dim3(16, 72, 1), blk, 0, stream>>>(
        nullptr, nullptr, WkvTb, kvb, vTb, 2048, 1024, 1024, 1024, 2048,
        0, 0, 0, 0, 0, 0, nullptr, 1152, cmem, mem, x);

    // new_cmem = mem[1024x4096] @ convwT + conv_b  (1024 x 4096 x 1024)
    mfma_gemm<0, 2, 0><<<dim3(8, 8, 1), blk, 0, stream>>>(
        mem, nullptr, convwTb, out_newcmem, nullptr, 1024, 4096, 4096, 4096, 1024,
        0, 0, 0, 0, 0, 0, conv_b, 0, nullptr, nullptr, nullptr);

    // ckv = new_cmem @ Wkv   (1024 x 1024 x 2048) + cvT bf16 secondary (vrows=128)
    mfma_gemm<0, 2, 3><<<dim3(16, 8, 1), blk, 0, stream>>>(
        out_newcmem, nullptr, WkvTb, ckv, cvT, 2048, 1024, 1024, 1024, 2048,
        0, 0, 0, 0, 0, 0, nullptr, 128, nullptr, nullptr, nullptr);

    // P = q @ pe^T -> rotated scatter into out_weights  (z=128: M=512,N=1152,K=64)
    mfma_gemm<0, 1, 1><<<dim3(9, 4, 128), blk, 0, stream>>>(
        q, pe, nullptr, out_weights, nullptr, 1152, 64, 1024, 64, 1152,
        524288, 64, 0, 73728, (long)16 * 589824, 589824, nullptr, 0, nullptr, nullptr, nullptr);

    // dots = 0.125*q@k^T + Prot -> out_weights (pre-softmax)
    mfma_gemm<0, 1, 2><<<dim3(9, 4, 128), blk, 0, stream>>>(
        q, kvb, nullptr, out_weights, nullptr, 1152, 64, 1024, 2048, 1152,
        524288, 64, (long)1152 * 2048, 64, (long)16 * 589824, 589824, nullptr, 0, nullptr, nullptr, nullptr);

    // softmax in place
    softmax_kernel<<<dim3(65536), blk, 0, stream>>>(out_weights);

    // out = attn @ v -> oat  (z=128: M=512,N=64,K=1152), B = vTb bf16
    mfma_gemm<0, 2, 0><<<dim3(1, 4, 128), blk, 0, stream>>>(
        out_weights, nullptr, vTb, oat, nullptr, 64, 1152, 1152, 1152, 1024,
        (long)16 * 589824, 589824, (long)16 * 64 * 1152, (long)64 * 1152, 524288, 64,
        nullptr, 0, nullptr, nullptr, nullptr);

    // logits = oat @ Wout + bout  (4096 x 1024 x 1024)
    mfma_gemm<0, 2, 0><<<dim3(8, 32, 1), blk, 0, stream>>>(
        oat, nullptr, WoutTb, out_logits, nullptr, 1024, 1024, 1024, 1024, 1024,
        0, 0, 0, 0, 0, 0, bout, 0, nullptr, nullptr, nullptr);

    // new_mem = x
    copy_kernel<<<dim3(4096), blk, 0, stream>>>(out_newmem, x, 1048576);

    // aux loss (MFMA flash attention x2)
    aux_mfma_kernel<<<dim3(4, 128), blk, 0, stream>>>(q, kvb, ckv, vTb, cvT, partials);
    aux_reduce_kernel<<<dim3(1), blk, 0, stream>>>(partials, out_aux);
}